// Round 9
// baseline (91.985 us; speedup 1.0000x reference)
//
#include <hip/hip_runtime.h>
#include <math.h>

#define D_MODEL   2048
#define N_EXPERTS 64
#define TOP_K     8
#define N_TOKENS  16384
#define NTHREADS  256
// ws layout (R2-HW-proven): [kstep 0..63][fr 0..3][ver 0..2][lane 0..63][4 dw]
#define WS_NEED   (64*4*3*64*16)   // 786432 bytes

typedef __attribute__((ext_vector_type(8))) short bf16x8;
typedef __attribute__((ext_vector_type(4))) float f32x4;
typedef __attribute__((ext_vector_type(4))) int   i32x4;

union FragU { i32x4 i; bf16x8 h; };

// exact 3-way truncation split: x == h+m+l + eps, |eps| <= 2^-24 |x|
__device__ __forceinline__ void split3(float x, unsigned &h, unsigned &m, unsigned &l) {
    unsigned ux = __float_as_uint(x);
    h = ux & 0xffff0000u;
    float mf = x - __uint_as_float(h);       // exact (Sterbenz)
    unsigned um = __float_as_uint(mf) & 0xffff0000u;
    float lf = mf - __uint_as_float(um);     // exact
    m = um;
    l = __float_as_uint(lf) & 0xffff0000u;
}

// ---- verbatim from R2 (HW-proven numerics + layout) ----
__global__ __launch_bounds__(256) void pack_w_kernel(const float* __restrict__ gw,
                                                     unsigned* __restrict__ wp) {
    const int g    = blockIdx.x * 256 + threadIdx.x;   // 0..196607
    const int d    = g & 3;
    const int lane = (g >> 2) & 63;
    const int rest = g >> 8;                           // 0..767
    const int v    = rest % 3;
    const int t    = rest / 3;                         // ks*4 + fr
    const int fr   = t & 3;
    const int ks   = t >> 2;
    const int e    = fr * 16 + (lane & 15);            // B col = lane&15
    const int k    = ks * 32 + (lane >> 4) * 8 + 2 * d;
    const float w0 = gw[(size_t)e * D_MODEL + k];
    const float w1 = gw[(size_t)e * D_MODEL + k + 1];
    unsigned h0, m0, l0, h1, m1, l1;
    split3(w0, h0, m0, l0);
    split3(w1, h1, m1, l1);
    const unsigned c0 = (v == 0) ? h0 : ((v == 1) ? m0 : l0);
    const unsigned c1 = (v == 0) ? h1 : ((v == 1) ? m1 : l1);
    wp[g] = (c0 >> 16) | c1;                           // low short = elem0
}

__device__ __forceinline__ void splitpack(const float4 a, const float4 b,
                                          FragU &ph, FragU &pm, FragU &pl) {
    const float f[8] = {a.x, a.y, a.z, a.w, b.x, b.y, b.z, b.w};
#pragma unroll
    for (int d = 0; d < 4; ++d) {
        unsigned h0, m0, l0, h1, m1, l1;
        split3(f[2 * d],     h0, m0, l0);
        split3(f[2 * d + 1], h1, m1, l1);
        ph.i[d] = (int)((h0 >> 16) | h1);
        pm.i[d] = (int)((m0 >> 16) | m1);
        pl.i[d] = (int)((l0 >> 16) | l1);
    }
}

#define MFMA(A_, B_, C_) C_ = __builtin_amdgcn_mfma_f32_16x16x32_bf16((A_).h, (B_).h, C_, 0, 0, 0)

// Geometry: block = 16 tokens x 64 experts x full K; 4 waves =
// (expert half eh) x (K half kh). Wave: 2 expert frags x 32 ksteps.
// Software pipeline: named B/C register sets (6 i32x4 each), loads for s+2
// issued AFTER the MFMAs that consume the same registers (WAR pins order),
// sched_barrier(0) per half-iteration. Compiler then emits counted vmcnt(8)
// waits with ~1.5 iterations of latency cover at 4 waves/SIMD. No barriers.
__global__ __launch_bounds__(NTHREADS, 4) void router_mfma(
    const float* __restrict__ x, const unsigned* __restrict__ wp,
    float* __restrict__ out)
{
    // partials: [kh:2][tok:16][expert:64] stride 68 (2-way bank = free, m136)
    __shared__ __align__(16) float part[2 * 1088 + 32];

    const int tid  = threadIdx.x;
    const int lane = tid & 63;
    const int q    = tid >> 6;          // 0..3
    const int eh   = q & 1;             // expert half
    const int kh   = q >> 1;            // K half
    const int m0   = blockIdx.x * 16;

    const int lrow = lane & 15;         // A row / C col
    const int lk   = lane >> 4;         // k-group 0..3

    // A: lane reads x[m0+lrow][kh*1024 + s*32 + lk*8 .. +8]
    const float* xa = x + (size_t)(m0 + lrow) * D_MODEL + kh * 1024 + lk * 8;
    // B: frags fr = eh*2, eh*2+1 ; dword offset ((ks*4+fr)*3)*256 + lane*4
    const unsigned* wb = wp + (size_t)kh * 32 * 3072 + eh * 1536 + lane * 4;

    f32x4 acc0a = {0.f,0.f,0.f,0.f}, acc0b = acc0a;
    f32x4 acc1a = acc0a, acc1b = acc0a;

    i32x4 B0h, B0m, B0l, B1h, B1m, B1l;   // even-s set
    i32x4 C0h, C0m, C0l, C1h, C1m, C1l;   // odd-s set
    float4 Aa0, Ab0, Aa1, Ab1;

#define LOADB(s_, H0,M0,L0,H1,M1,L1)                                         \
    {   const unsigned* bt_ = wb + (size_t)(s_) * 3072;                      \
        H0 = *(const i32x4*)(bt_ +    0);                                    \
        M0 = *(const i32x4*)(bt_ +  256);                                    \
        L0 = *(const i32x4*)(bt_ +  512);                                    \
        H1 = *(const i32x4*)(bt_ +  768);                                    \
        M1 = *(const i32x4*)(bt_ + 1024);                                    \
        L1 = *(const i32x4*)(bt_ + 1280); }

    // prologue: ksteps 0 and 1 in flight
    LOADB(0, B0h,B0m,B0l,B1h,B1m,B1l);
    Aa0 = *(const float4*)(xa);
    Ab0 = *(const float4*)(xa + 4);
    LOADB(1, C0h,C0m,C0l,C1h,C1m,C1l);
    Aa1 = *(const float4*)(xa + 32);
    Ab1 = *(const float4*)(xa + 36);
    __builtin_amdgcn_sched_barrier(0);

    for (int s = 0; s < 32; s += 2) {
        {   // even half-iteration: consume A0 + B-set, prefetch s+2 into them
            FragU ah, am_, al;
            splitpack(Aa0, Ab0, ah, am_, al);
            FragU bh, bm, bl, ch, cm, cl;
            bh.i = B0h; bm.i = B0m; bl.i = B0l;
            ch.i = B1h; cm.i = B1m; cl.i = B1l;
            MFMA(ah, bh, acc0a);  MFMA(ah, ch, acc1a);
            MFMA(am_, bh, acc0a); MFMA(am_, ch, acc1a);
            MFMA(al, bh, acc0a);  MFMA(al, ch, acc1a);
            MFMA(ah, bm, acc0b);  MFMA(ah, cm, acc1b);
            MFMA(am_, bm, acc0b); MFMA(am_, cm, acc1b);
            MFMA(ah, bl, acc0b);  MFMA(ah, cl, acc1b);
            if (s < 30) {
                LOADB(s + 2, B0h,B0m,B0l,B1h,B1m,B1l);
                Aa0 = *(const float4*)(xa + (s + 2) * 32);
                Ab0 = *(const float4*)(xa + (s + 2) * 32 + 4);
            }
            __builtin_amdgcn_sched_barrier(0);
        }
        {   // odd half-iteration: consume A1 + C-set, prefetch s+3 into them
            FragU ah, am_, al;
            splitpack(Aa1, Ab1, ah, am_, al);
            FragU bh, bm, bl, ch, cm, cl;
            bh.i = C0h; bm.i = C0m; bl.i = C0l;
            ch.i = C1h; cm.i = C1m; cl.i = C1l;
            MFMA(ah, bh, acc0a);  MFMA(ah, ch, acc1a);
            MFMA(am_, bh, acc0a); MFMA(am_, ch, acc1a);
            MFMA(al, bh, acc0a);  MFMA(al, ch, acc1a);
            MFMA(ah, bm, acc0b);  MFMA(ah, cm, acc1b);
            MFMA(am_, bm, acc0b); MFMA(am_, cm, acc1b);
            MFMA(ah, bl, acc0b);  MFMA(ah, cl, acc1b);
            if (s < 30) {
                LOADB(s + 3, C0h,C0m,C0l,C1h,C1m,C1l);
                Aa1 = *(const float4*)(xa + (s + 3) * 32);
                Ab1 = *(const float4*)(xa + (s + 3) * 32 + 4);
            }
            __builtin_amdgcn_sched_barrier(0);
        }
    }
#undef LOADB

    // partials: token = lk*4+reg, expert = fr*16 + lrow (R2-HW-proven C layout)
    {
        float* ps = part + kh * 1088;
#pragma unroll
        for (int reg = 0; reg < 4; ++reg) {
            const int tok = lk * 4 + reg;
            ps[tok * 68 + eh * 32 +  0 + lrow] = acc0a[reg] + acc0b[reg];
            ps[tok * 68 + eh * 32 + 16 + lrow] = acc1a[reg] + acc1b[reg];
        }
    }
    __syncthreads();

    // reduce 2 K-halves: thread j -> (tok=j>>4, e0=(j&15)*4)
    {
        const int tok = tid >> 4;
        const int e0  = (tid & 15) * 4;
        const int o   = tok * 68 + e0;
        float4 s0 = *(const float4*)(part + o);
        float4 s1 = *(const float4*)(part + 1088 + o);
        float4 r = make_float4(s0.x + s1.x, s0.y + s1.y,
                               s0.z + s1.z, s0.w + s1.w);
        *(float4*)(part + o) = r;     // slice 0 becomes lt
    }
    __syncthreads();

    float* lt   = part;               // [tok*68 + e]
    float* smax = part + 2 * 1088;
    float* srs  = smax + 16;

    float* out_idx = out;
    float* out_w   = out + (size_t)N_TOKENS * TOP_K;
    float* out_p   = out + (size_t)2 * N_TOKENS * TOP_K;
    float* out_l   = out_p + (size_t)N_TOKENS * N_EXPERTS;

    if (tid < 16) {
        const int t = tid;
        float tv[TOP_K];
        int   ti[TOP_K];
#pragma unroll
        for (int i = 0; i < TOP_K; ++i) { tv[i] = -INFINITY; ti[i] = 0; }
        float m = -INFINITY;

        for (int e = 0; e < N_EXPERTS; ++e) {
            const float v = lt[t * 68 + e];
            m = fmaxf(m, v);
            if (v > tv[TOP_K - 1]) {
#pragma unroll
                for (int j = TOP_K - 1; j >= 1; --j) {
                    const bool shift = (v > tv[j - 1]);
                    const bool here  = (v > tv[j]);
                    const float ntv = shift ? tv[j - 1] : (here ? v : tv[j]);
                    const int   nti = shift ? ti[j - 1] : (here ? e : ti[j]);
                    tv[j] = ntv; ti[j] = nti;
                }
                if (v > tv[0]) { tv[0] = v; ti[0] = e; }
            }
        }

        float s = 0.f;
        for (int e = 0; e < N_EXPERTS; ++e) s += expf(lt[t * 68 + e] - m);
        const float rs = 1.f / s;
        smax[t] = m;
        srs[t]  = rs;

        float ex[TOP_K];
        float wsum = 0.f;
#pragma unroll
        for (int i = 0; i < TOP_K; ++i) { ex[i] = expf(tv[i] - tv[0]); wsum += ex[i]; }
        const float rw = 1.f / wsum;

        const int tok = m0 + t;
#pragma unroll
        for (int i = 0; i < TOP_K; ++i) {
            out_idx[(size_t)tok * TOP_K + i] = (float)ti[i];
            out_w  [(size_t)tok * TOP_K + i] = ex[i] * rw;
        }
    }
    __syncthreads();

    // 16x64 floats = 256 threads x 1 float4, coalesced
    {
        const int f = tid * 4;
        const int t = f >> 6;
        const int e = f & 63;
        const float l0 = lt[t * 68 + e + 0];
        const float l1 = lt[t * 68 + e + 1];
        const float l2 = lt[t * 68 + e + 2];
        const float l3 = lt[t * 68 + e + 3];
        const float mm = smax[t];
        const float rr = srs[t];
        float4 pv = make_float4(expf(l0 - mm) * rr, expf(l1 - mm) * rr,
                                expf(l2 - mm) * rr, expf(l3 - mm) * rr);
        float4 lv = make_float4(l0, l1, l2, l3);
        const size_t gbase = (size_t)m0 * N_EXPERTS + f;
        *(float4*)(out_p + gbase) = pv;
        *(float4*)(out_l + gbase) = lv;
    }
}

// ---------------- fallback (R0-proven fp32 path) if ws too small ----------------
__global__ __launch_bounds__(512) void router_fallback(
    const float* __restrict__ x, const float* __restrict__ gw,
    float* __restrict__ out)
{
    __shared__ float xs[64][33];
    __shared__ float wsh[N_EXPERTS][36];
    __shared__ float lt[64][N_EXPERTS + 1];
    __shared__ float smax[64], srs[64];

    const int tid  = threadIdx.x;
    const int lane = tid & 63;
    const int wv   = tid >> 6;
    const int m0   = blockIdx.x * 64;
    const int srow = tid >> 3;
    const int skq  = (tid & 7) * 4;

    const float* xsrc = x  + (size_t)(m0 + srow) * D_MODEL + skq;
    const float* wsrc = gw + (size_t)srow        * D_MODEL + skq;
    float4 xr = *(const float4*)(xsrc);
    float4 wr = *(const float4*)(wsrc);

    float acc[8];
#pragma unroll
    for (int i = 0; i < 8; ++i) acc[i] = 0.f;
    const int e0 = wv * 8;

    for (int c = 0; c < D_MODEL / 32; ++c) {
        xs[srow][skq] = xr.x; xs[srow][skq+1] = xr.y; xs[srow][skq+2] = xr.z; xs[srow][skq+3] = xr.w;
        *(float4*)&wsh[srow][skq] = wr;
        __syncthreads();
        if (c + 1 < D_MODEL / 32) {
            xr = *(const float4*)(xsrc + (c + 1) * 32);
            wr = *(const float4*)(wsrc + (c + 1) * 32);
        }
#pragma unroll 8
        for (int k4 = 0; k4 < 8; ++k4) {
            const float4 xv = *(const float4*)&xs[lane][k4 * 4];
#pragma unroll
            for (int e = 0; e < 8; ++e) {
                const float4 w4 = *(const float4*)&wsh[e0 + e][k4 * 4];
                acc[e] = fmaf(xv.x, w4.x, fmaf(xv.y, w4.y, fmaf(xv.z, w4.z, fmaf(xv.w, w4.w, acc[e]))));
            }
        }
        __syncthreads();
    }
#pragma unroll
    for (int e = 0; e < 8; ++e) lt[lane][e0 + e] = acc[e];
    __syncthreads();

    float* out_idx = out;
    float* out_w   = out + (size_t)N_TOKENS * TOP_K;
    float* out_p   = out + (size_t)2 * N_TOKENS * TOP_K;
    float* out_l   = out_p + (size_t)N_TOKENS * N_EXPERTS;

    if (tid < 64) {
        const int t = tid;
        float tv[TOP_K]; int ti[TOP_K];
#pragma unroll
        for (int i = 0; i < TOP_K; ++i) { tv[i] = -INFINITY; ti[i] = 0; }
        float m = -INFINITY;
        for (int e = 0; e < N_EXPERTS; ++e) {
            const float v = lt[t][e];
            m = fmaxf(m, v);
            if (v > tv[TOP_K - 1]) {
#pragma unroll
                for (int j = TOP_K - 1; j >= 1; --j) {
                    const bool shift = (v > tv[j - 1]);
                    const bool here  = (v > tv[j]);
                    const float ntv = shift ? tv[j - 1] : (here ? v : tv[j]);
                    const int   nti = shift ? ti[j - 1] : (here ? e : ti[j]);
                    tv[j] = ntv; ti[j] = nti;
                }
                if (v > tv[0]) { tv[0] = v; ti[0] = e; }
            }
        }
        float s = 0.f;
        for (int e = 0; e < N_EXPERTS; ++e) s += expf(lt[t][e] - m);
        const float rs = 1.f / s;
        smax[t] = m; srs[t] = rs;
        float ex[TOP_K]; float wsum = 0.f;
#pragma unroll
        for (int i = 0; i < TOP_K; ++i) { ex[i] = expf(tv[i] - tv[0]); wsum += ex[i]; }
        const float rw = 1.f / wsum;
        const int tok = m0 + t;
#pragma unroll
        for (int i = 0; i < TOP_K; ++i) {
            out_idx[(size_t)tok * TOP_K + i] = (float)ti[i];
            out_w  [(size_t)tok * TOP_K + i] = ex[i] * rw;
        }
    }
    __syncthreads();
#pragma unroll
    for (int rep = 0; rep < 2; ++rep) {
        const int f = rep * (512 * 4) + tid * 4;
        const int t = f >> 6;
        const int e = f & 63;
        const float l0 = lt[t][e], l1 = lt[t][e+1], l2 = lt[t][e+2], l3 = lt[t][e+3];
        const float mm = smax[t], rr = srs[t];
        float4 pv = make_float4(expf(l0-mm)*rr, expf(l1-mm)*rr, expf(l2-mm)*rr, expf(l3-mm)*rr);
        float4 lv = make_float4(l0, l1, l2, l3);
        const size_t gbase = (size_t)m0 * N_EXPERTS + f;
        *(float4*)(out_p + gbase) = pv;
        *(float4*)(out_l + gbase) = lv;
    }
}

extern "C" void kernel_launch(void* const* d_in, const int* in_sizes, int n_in,
                              void* d_out, int out_size, void* d_ws, size_t ws_size,
                              hipStream_t stream) {
    const float* x  = (const float*)d_in[0];
    const float* gw = (const float*)d_in[1];
    float* out = (float*)d_out;
    if (ws_size >= (size_t)WS_NEED) {
        unsigned* wp = (unsigned*)d_ws;
        pack_w_kernel<<<dim3(WS_NEED / 4 / 256), dim3(256), 0, stream>>>(gw, wp);
        router_mfma<<<dim3(N_TOKENS / 16), dim3(NTHREADS), 0, stream>>>(x, wp, out);
    } else {
        router_fallback<<<dim3(N_TOKENS / 64), dim3(512), 0, stream>>>(x, gw, out);
    }
}